// Round 1
// baseline (726.421 us; speedup 1.0000x reference)
//
#include <hip/hip_runtime.h>
#include <hip/hip_bf16.h>
#include <cstdint>
#include <cstddef>

#define H    50
#define G4   200      // 4*H gates
#define TT   256      // timesteps
#define BATCH 512
#define KDIM 144      // layer-0 input dim
#define ODIM 144      // FC output dim

__device__ __forceinline__ float sigm(float x) {
    return 1.0f / (1.0f + __expf(-x));
}
__device__ __forceinline__ float tanhx(float x) {
    // tanh(x) = 1 - 2/(e^{2x}+1); graceful at +-inf of exp
    float e = __expf(2.0f * x);
    return 1.0f - 2.0f / (e + 1.0f);
}

// ---------------- Kernel 1: XP[M,200] = X[M,144] @ W_ih0^T  (W_ih0: [200,144]) -------
// BM=64, BN=64 (4 n-tiles cover 200, last partially masked), BK=16, 256 thr, 4x4 tile.
#define BM 64
#define BN 64
#define BK 16
__global__ __launch_bounds__(256) void xproj_gemm(
    const float* __restrict__ X, const float* __restrict__ W, float* __restrict__ XP)
{
    __shared__ float Xs[BK][BM + 4];   // +4 pad: stride 68 dwords, keeps float4 align
    __shared__ float Ws[BK][BN + 4];
    const int tid = threadIdx.x;
    const int m0 = blockIdx.x * BM;
    const int n0 = blockIdx.y * BN;
    const int kk = tid & 15;          // staging: k within tile
    const int rr = tid >> 4;          // staging: row group
    const int nt = tid & 15;          // compute: n-thread (fast -> coalesced stores)
    const int mt = tid >> 4;          // compute: m-thread
    float acc[4][4] = {};
    for (int k0 = 0; k0 < KDIM; k0 += BK) {
        #pragma unroll
        for (int i = 0; i < 4; ++i) {
            const int m = rr + i * 16;
            Xs[kk][m] = X[(size_t)(m0 + m) * KDIM + k0 + kk];
            const int n = n0 + rr + i * 16;
            Ws[kk][rr + i * 16] = (n < G4) ? W[(size_t)n * KDIM + k0 + kk] : 0.0f;
        }
        __syncthreads();
        #pragma unroll
        for (int k = 0; k < BK; ++k) {
            const float4 a  = *(const float4*)&Xs[k][mt * 4];
            const float4 bb = *(const float4*)&Ws[k][nt * 4];
            const float av[4] = {a.x, a.y, a.z, a.w};
            const float bv[4] = {bb.x, bb.y, bb.z, bb.w};
            #pragma unroll
            for (int i = 0; i < 4; ++i)
                #pragma unroll
                for (int j = 0; j < 4; ++j)
                    acc[i][j] += av[i] * bv[j];
        }
        __syncthreads();
    }
    const int n = n0 + nt * 4;
    if (n + 3 < G4) {
        #pragma unroll
        for (int i = 0; i < 4; ++i) {
            const int m = m0 + mt * 4 + i;
            float4 v = make_float4(acc[i][0], acc[i][1], acc[i][2], acc[i][3]);
            *(float4*)&XP[(size_t)m * G4 + n] = v;
        }
    }
}

// ---------------- Kernel 2: persistent per-batch-row 2-layer LSTM + fused FC --------
// 512 WGs (1 batch row each, 2 WG/CU), 256 threads. Thread g<200 owns gate row g with
// W_hh0/W_ih1/W_hh1 rows in registers (150 VGPR). h in LDS (broadcast reads), c in
// registers of threads 0..49. Layer 1 runs one step behind layer 0 -> 2 barriers/step.
__global__ __launch_bounds__(256, 2) void lstm_persist(
    const float* __restrict__ XP,
    const float* __restrict__ Whh0,
    const float* __restrict__ Wih1,
    const float* __restrict__ Whh1,
    const float* __restrict__ bih0, const float* __restrict__ bhh0,
    const float* __restrict__ bih1, const float* __restrict__ bhh1,
    const float* __restrict__ Wfc,  const float* __restrict__ bfc,
    float* __restrict__ out)
{
    const int b = blockIdx.x;
    const int tid = threadIdx.x;
    const bool act = tid < G4;
    const int g = act ? tid : (G4 - 1);
    __shared__ __align__(16) float h0s[52];
    __shared__ __align__(16) float h1s[52];
    __shared__ __align__(16) float gs0[G4];
    __shared__ __align__(16) float gs1[G4];
    float w0[H], w1i[H], w1h[H];
    #pragma unroll
    for (int k = 0; k < H; ++k) {
        w0[k]  = Whh0[(size_t)g * H + k];
        w1i[k] = Wih1[(size_t)g * H + k];
        w1h[k] = Whh1[(size_t)g * H + k];
    }
    const float bias0 = bih0[g] + bhh0[g];
    const float bias1 = bih1[g] + bhh1[g];
    if (tid < 52) { h0s[tid] = 0.0f; h1s[tid] = 0.0f; }
    float c0 = 0.0f, c1 = 0.0f;
    __syncthreads();
    const float* xpb = XP + (size_t)b * (TT * G4);
    float xp = act ? xpb[g] : 0.0f;   // prefetch t=0
    for (int t = 0; t < TT; ++t) {
        float xpn = 0.0f;
        if (act && t < TT - 1) xpn = xpb[(size_t)(t + 1) * G4 + g];  // prefetch t+1
        // ---- stage A: gates0(t) [needs h0(t-1)] and gates1(t-1) [needs h0(t-1), h1(t-2)]
        float s0 = bias0 + xp, s1 = 0.f, s2 = 0.f, s3 = 0.f;
        float u0 = bias1,      u1 = 0.f, u2 = 0.f, u3 = 0.f;
        #pragma unroll
        for (int q = 0; q < 12; ++q) {
            const float4 ha = *(const float4*)&h0s[q * 4];   // broadcast, conflict-free
            const float4 hb = *(const float4*)&h1s[q * 4];
            s0 += w0[q*4+0] * ha.x;
            s1 += w0[q*4+1] * ha.y;
            s2 += w0[q*4+2] * ha.z;
            s3 += w0[q*4+3] * ha.w;
            u0 += w1i[q*4+0] * ha.x + w1h[q*4+0] * hb.x;
            u1 += w1i[q*4+1] * ha.y + w1h[q*4+1] * hb.y;
            u2 += w1i[q*4+2] * ha.z + w1h[q*4+2] * hb.z;
            u3 += w1i[q*4+3] * ha.w + w1h[q*4+3] * hb.w;
        }
        {
            const float2 ha = *(const float2*)&h0s[48];
            const float2 hb = *(const float2*)&h1s[48];
            s0 += w0[48] * ha.x;                    s1 += w0[49] * ha.y;
            u0 += w1i[48] * ha.x + w1h[48] * hb.x;  u1 += w1i[49] * ha.y + w1h[49] * hb.y;
        }
        if (act) { gs0[tid] = (s0 + s1) + (s2 + s3); gs1[tid] = (u0 + u1) + (u2 + u3); }
        __syncthreads();
        // ---- stage B: elementwise layer0(t) and layer1(t-1)
        if (tid < H) {
            const float gi = sigm(gs0[tid]);
            const float gf = sigm(gs0[H + tid]);
            const float gg = tanhx(gs0[2*H + tid]);
            const float go = sigm(gs0[3*H + tid]);
            c0 = gf * c0 + gi * gg;
            h0s[tid] = go * tanhx(c0);
            if (t > 0) {
                const float qi = sigm(gs1[tid]);
                const float qf = sigm(gs1[H + tid]);
                const float qg = tanhx(gs1[2*H + tid]);
                const float qo = sigm(gs1[3*H + tid]);
                c1 = qf * c1 + qi * qg;
                h1s[tid] = qo * tanhx(c1);
            }
        }
        __syncthreads();
        xp = xpn;
    }
    // ---- pipeline tail: gates1(255) + elementwise layer1(255)
    {
        float u0 = bias1, u1 = 0.f, u2 = 0.f, u3 = 0.f;
        #pragma unroll
        for (int q = 0; q < 12; ++q) {
            const float4 ha = *(const float4*)&h0s[q * 4];
            const float4 hb = *(const float4*)&h1s[q * 4];
            u0 += w1i[q*4+0] * ha.x + w1h[q*4+0] * hb.x;
            u1 += w1i[q*4+1] * ha.y + w1h[q*4+1] * hb.y;
            u2 += w1i[q*4+2] * ha.z + w1h[q*4+2] * hb.z;
            u3 += w1i[q*4+3] * ha.w + w1h[q*4+3] * hb.w;
        }
        {
            const float2 ha = *(const float2*)&h0s[48];
            const float2 hb = *(const float2*)&h1s[48];
            u0 += w1i[48] * ha.x + w1h[48] * hb.x;
            u1 += w1i[49] * ha.y + w1h[49] * hb.y;
        }
        if (act) gs1[tid] = (u0 + u1) + (u2 + u3);
        __syncthreads();
        if (tid < H) {
            const float qi = sigm(gs1[tid]);
            const float qf = sigm(gs1[H + tid]);
            const float qg = tanhx(gs1[2*H + tid]);
            const float qo = sigm(gs1[3*H + tid]);
            c1 = qf * c1 + qi * qg;
            h1s[tid] = qo * tanhx(c1);
        }
        __syncthreads();
    }
    // ---- fused FC on the final hidden state h2[T-1]
    if (tid < ODIM) {
        float s = bfc[tid];
        #pragma unroll
        for (int k = 0; k < H; ++k) s += Wfc[(size_t)tid * H + k] * h1s[k];
        out[(size_t)b * ODIM + tid] = s;
    }
}

extern "C" void kernel_launch(void* const* d_in, const int* in_sizes, int n_in,
                              void* d_out, int out_size, void* d_ws, size_t ws_size,
                              hipStream_t stream) {
    const float* x    = (const float*)d_in[0];
    const float* wih0 = (const float*)d_in[1];
    const float* whh0 = (const float*)d_in[2];
    const float* bih0 = (const float*)d_in[3];
    const float* bhh0 = (const float*)d_in[4];
    const float* wih1 = (const float*)d_in[5];
    const float* whh1 = (const float*)d_in[6];
    const float* bih1 = (const float*)d_in[7];
    const float* bhh1 = (const float*)d_in[8];
    const float* wfc  = (const float*)d_in[9];
    const float* bfc  = (const float*)d_in[10];
    float* outp = (float*)d_out;
    float* XP = (float*)d_ws;   // 131072 x 200 fp32 = 104.86 MB scratch

    dim3 g1(BATCH * TT / BM, (G4 + BN - 1) / BN);   // (2048, 4)
    xproj_gemm<<<g1, 256, 0, stream>>>(x, wih0, XP);
    lstm_persist<<<BATCH, 256, 0, stream>>>(XP, whh0, wih1, whh1,
                                            bih0, bhh0, bih1, bhh1,
                                            wfc, bfc, outp);
}

// Round 2
// 711.974 us; speedup vs baseline: 1.0203x; 1.0203x over previous
//
#include <hip/hip_runtime.h>
#include <hip/hip_bf16.h>
#include <cstdint>
#include <cstddef>

#define H    50
#define G4   200      // 4*H gates
#define TT   256      // timesteps
#define BATCH 512
#define KDIM 144      // layer-0 input dim
#define ODIM 144      // FC output dim

__device__ __forceinline__ float sigm(float x) {
    return 1.0f / (1.0f + __expf(-x));
}
__device__ __forceinline__ float tanhx(float x) {
    float e = __expf(2.0f * x);
    return 1.0f - 2.0f / (e + 1.0f);
}

// ---------------- Kernel 1: XP[M,200] = X[M,144] @ W_ih0^T  (W_ih0: [200,144]) -------
// BM=128, BN=64 (4 n-tiles cover 200, last mostly masked), BK=16, 256 thr, 8x4 tile.
#define BM 128
#define BN 64
#define BK 16
__global__ __launch_bounds__(256) void xproj_gemm(
    const float* __restrict__ X, const float* __restrict__ W, float* __restrict__ XP)
{
    __shared__ float Xs[BK][BM + 4];   // stride 132 dwords
    __shared__ float Ws[BK][BN + 4];   // stride 68 dwords
    const int tid = threadIdx.x;
    const int m0 = blockIdx.x * BM;
    const int n0 = blockIdx.y * BN;
    const int kk = tid & 15;          // staging: k within tile
    const int rr = tid >> 4;          // staging: row group (0..15)
    const int nt = tid & 15;          // compute: n-thread (4 cols)
    const int mt = tid >> 4;          // compute: m-thread (8 rows)
    float acc[8][4] = {};
    for (int k0 = 0; k0 < KDIM; k0 += BK) {
        #pragma unroll
        for (int i = 0; i < 8; ++i) {
            const int m = rr + i * 16;
            Xs[kk][m] = X[(size_t)(m0 + m) * KDIM + k0 + kk];
        }
        #pragma unroll
        for (int i = 0; i < 4; ++i) {
            const int n = n0 + rr + i * 16;
            Ws[kk][rr + i * 16] = (n < G4) ? W[(size_t)n * KDIM + k0 + kk] : 0.0f;
        }
        __syncthreads();
        #pragma unroll
        for (int k = 0; k < BK; ++k) {
            const float4 a0 = *(const float4*)&Xs[k][mt * 8];
            const float4 a1 = *(const float4*)&Xs[k][mt * 8 + 4];
            const float4 bb = *(const float4*)&Ws[k][nt * 4];
            const float av[8] = {a0.x, a0.y, a0.z, a0.w, a1.x, a1.y, a1.z, a1.w};
            const float bv[4] = {bb.x, bb.y, bb.z, bb.w};
            #pragma unroll
            for (int i = 0; i < 8; ++i)
                #pragma unroll
                for (int j = 0; j < 4; ++j)
                    acc[i][j] += av[i] * bv[j];
        }
        __syncthreads();
    }
    const int n = n0 + nt * 4;
    if (n < G4) {   // G4 % 4 == 0, so a valid float4 iff n < G4
        #pragma unroll
        for (int i = 0; i < 8; ++i) {
            const int m = m0 + mt * 8 + i;
            float4 v = make_float4(acc[i][0], acc[i][1], acc[i][2], acc[i][3]);
            *(float4*)&XP[(size_t)m * G4 + n] = v;
        }
    }
}

// ---------------- Kernel 2: persistent 2-rows-per-WG 2-layer LSTM + fused FC --------
// 256 WGs (2 batch rows each, 1 WG/CU in one pass), 256 threads.
// Thread g<200 owns gate row g: W_hh0/W_ih1/W_hh1 rows in registers (150 VGPR),
// amortized over 2 batch rows. launch_bounds(256,1) -> 512 VGPR cap, no spill.
// Elementwise stage spread over all 4 waves: wave 0/1 = layer0 row 0/1 (owns c0),
// wave 2/3 = layer1 row 0/1 (owns c1). Layer 1 runs one step behind layer 0.
__global__ __launch_bounds__(256, 1) void lstm_persist(
    const float* __restrict__ XP,
    const float* __restrict__ Whh0,
    const float* __restrict__ Wih1,
    const float* __restrict__ Whh1,
    const float* __restrict__ bih0, const float* __restrict__ bhh0,
    const float* __restrict__ bih1, const float* __restrict__ bhh1,
    const float* __restrict__ Wfc,  const float* __restrict__ bfc,
    float* __restrict__ out)
{
    const int b0 = blockIdx.x * 2;
    const int tid = threadIdx.x;
    const int wave = tid >> 6;
    const int lane = tid & 63;
    const bool act = tid < G4;
    const int g = act ? tid : (G4 - 1);
    __shared__ __align__(16) float h0s[2][52];
    __shared__ __align__(16) float h1s[2][52];
    __shared__ __align__(16) float gs0[2][G4];
    __shared__ __align__(16) float gs1[2][G4];
    float w0[H], w1i[H], w1h[H];
    #pragma unroll
    for (int k = 0; k < H; ++k) {
        w0[k]  = Whh0[(size_t)g * H + k];
        w1i[k] = Wih1[(size_t)g * H + k];
        w1h[k] = Whh1[(size_t)g * H + k];
    }
    const float bias0 = bih0[g] + bhh0[g];
    const float bias1 = bih1[g] + bhh1[g];
    if (tid < 52) {
        h0s[0][tid] = 0.0f; h0s[1][tid] = 0.0f;
        h1s[0][tid] = 0.0f; h1s[1][tid] = 0.0f;
    }
    float c0 = 0.0f, c1 = 0.0f;   // c0 live in waves 0/1 (lane<50); c1 in waves 2/3
    __syncthreads();
    const float* xpb0 = XP + (size_t)b0 * (TT * G4);
    const float* xpb1 = xpb0 + (size_t)(TT * G4);
    float xpA = act ? xpb0[g] : 0.0f;   // prefetch t=0
    float xpB = act ? xpb1[g] : 0.0f;
    for (int t = 0; t < TT; ++t) {
        float xnA = 0.0f, xnB = 0.0f;
        if (act && t < TT - 1) {
            xnA = xpb0[(size_t)(t + 1) * G4 + g];
            xnB = xpb1[(size_t)(t + 1) * G4 + g];
        }
        // ---- stage A: gates0(t) [needs h0(t-1)] and gates1(t-1) [needs h0(t-1), h1(t-2)]
        float sA0 = bias0 + xpA, sA1 = 0.f, sA2 = 0.f, sA3 = 0.f;
        float sB0 = bias0 + xpB, sB1 = 0.f, sB2 = 0.f, sB3 = 0.f;
        float uA0 = bias1, uA1 = 0.f, uA2 = 0.f, uA3 = 0.f;
        float uB0 = bias1, uB1 = 0.f, uB2 = 0.f, uB3 = 0.f;
        #pragma unroll
        for (int q = 0; q < 12; ++q) {
            const float4 ha0 = *(const float4*)&h0s[0][q * 4];   // broadcast, conflict-free
            const float4 ha1 = *(const float4*)&h0s[1][q * 4];
            const float4 hb0 = *(const float4*)&h1s[0][q * 4];
            const float4 hb1 = *(const float4*)&h1s[1][q * 4];
            sA0 += w0[q*4+0] * ha0.x;  sB0 += w0[q*4+0] * ha1.x;
            sA1 += w0[q*4+1] * ha0.y;  sB1 += w0[q*4+1] * ha1.y;
            sA2 += w0[q*4+2] * ha0.z;  sB2 += w0[q*4+2] * ha1.z;
            sA3 += w0[q*4+3] * ha0.w;  sB3 += w0[q*4+3] * ha1.w;
            uA0 += w1i[q*4+0] * ha0.x + w1h[q*4+0] * hb0.x;
            uA1 += w1i[q*4+1] * ha0.y + w1h[q*4+1] * hb0.y;
            uA2 += w1i[q*4+2] * ha0.z + w1h[q*4+2] * hb0.z;
            uA3 += w1i[q*4+3] * ha0.w + w1h[q*4+3] * hb0.w;
            uB0 += w1i[q*4+0] * ha1.x + w1h[q*4+0] * hb1.x;
            uB1 += w1i[q*4+1] * ha1.y + w1h[q*4+1] * hb1.y;
            uB2 += w1i[q*4+2] * ha1.z + w1h[q*4+2] * hb1.z;
            uB3 += w1i[q*4+3] * ha1.w + w1h[q*4+3] * hb1.w;
        }
        {
            const float2 ha0 = *(const float2*)&h0s[0][48];
            const float2 ha1 = *(const float2*)&h0s[1][48];
            const float2 hb0 = *(const float2*)&h1s[0][48];
            const float2 hb1 = *(const float2*)&h1s[1][48];
            sA0 += w0[48] * ha0.x;  sA1 += w0[49] * ha0.y;
            sB0 += w0[48] * ha1.x;  sB1 += w0[49] * ha1.y;
            uA0 += w1i[48] * ha0.x + w1h[48] * hb0.x;
            uA1 += w1i[49] * ha0.y + w1h[49] * hb0.y;
            uB0 += w1i[48] * ha1.x + w1h[48] * hb1.x;
            uB1 += w1i[49] * ha1.y + w1h[49] * hb1.y;
        }
        if (act) {
            gs0[0][tid] = (sA0 + sA1) + (sA2 + sA3);
            gs0[1][tid] = (sB0 + sB1) + (sB2 + sB3);
            gs1[0][tid] = (uA0 + uA1) + (uA2 + uA3);
            gs1[1][tid] = (uB0 + uB1) + (uB2 + uB3);
        }
        __syncthreads();
        // ---- stage B: elementwise — 4 waves work in parallel
        if (lane < H) {
            if (wave < 2) {
                const int r = wave;
                const float gi = sigm(gs0[r][lane]);
                const float gf = sigm(gs0[r][H + lane]);
                const float gg = tanhx(gs0[r][2*H + lane]);
                const float go = sigm(gs0[r][3*H + lane]);
                c0 = gf * c0 + gi * gg;
                h0s[r][lane] = go * tanhx(c0);
            } else if (t > 0) {
                const int r = wave - 2;
                const float qi = sigm(gs1[r][lane]);
                const float qf = sigm(gs1[r][H + lane]);
                const float qg = tanhx(gs1[r][2*H + lane]);
                const float qo = sigm(gs1[r][3*H + lane]);
                c1 = qf * c1 + qi * qg;
                h1s[r][lane] = qo * tanhx(c1);
            }
        }
        __syncthreads();
        xpA = xnA; xpB = xnB;
    }
    // ---- pipeline tail: gates1(TT-1) for both rows + elementwise layer1
    {
        float uA0 = bias1, uA1 = 0.f, uA2 = 0.f, uA3 = 0.f;
        float uB0 = bias1, uB1 = 0.f, uB2 = 0.f, uB3 = 0.f;
        #pragma unroll
        for (int q = 0; q < 12; ++q) {
            const float4 ha0 = *(const float4*)&h0s[0][q * 4];
            const float4 ha1 = *(const float4*)&h0s[1][q * 4];
            const float4 hb0 = *(const float4*)&h1s[0][q * 4];
            const float4 hb1 = *(const float4*)&h1s[1][q * 4];
            uA0 += w1i[q*4+0] * ha0.x + w1h[q*4+0] * hb0.x;
            uA1 += w1i[q*4+1] * ha0.y + w1h[q*4+1] * hb0.y;
            uA2 += w1i[q*4+2] * ha0.z + w1h[q*4+2] * hb0.z;
            uA3 += w1i[q*4+3] * ha0.w + w1h[q*4+3] * hb0.w;
            uB0 += w1i[q*4+0] * ha1.x + w1h[q*4+0] * hb1.x;
            uB1 += w1i[q*4+1] * ha1.y + w1h[q*4+1] * hb1.y;
            uB2 += w1i[q*4+2] * ha1.z + w1h[q*4+2] * hb1.z;
            uB3 += w1i[q*4+3] * ha1.w + w1h[q*4+3] * hb1.w;
        }
        {
            const float2 ha0 = *(const float2*)&h0s[0][48];
            const float2 ha1 = *(const float2*)&h0s[1][48];
            const float2 hb0 = *(const float2*)&h1s[0][48];
            const float2 hb1 = *(const float2*)&h1s[1][48];
            uA0 += w1i[48] * ha0.x + w1h[48] * hb0.x;
            uA1 += w1i[49] * ha0.y + w1h[49] * hb0.y;
            uB0 += w1i[48] * ha1.x + w1h[48] * hb1.x;
            uB1 += w1i[49] * ha1.y + w1h[49] * hb1.y;
        }
        if (act) {
            gs1[0][tid] = (uA0 + uA1) + (uA2 + uA3);
            gs1[1][tid] = (uB0 + uB1) + (uB2 + uB3);
        }
        __syncthreads();
        if (lane < H && wave >= 2) {
            const int r = wave - 2;
            const float qi = sigm(gs1[r][lane]);
            const float qf = sigm(gs1[r][H + lane]);
            const float qg = tanhx(gs1[r][2*H + lane]);
            const float qo = sigm(gs1[r][3*H + lane]);
            c1 = qf * c1 + qi * qg;
            h1s[r][lane] = qo * tanhx(c1);
        }
        __syncthreads();
    }
    // ---- fused FC on the final hidden states
    if (tid < ODIM) {
        #pragma unroll
        for (int r = 0; r < 2; ++r) {
            float s = bfc[tid];
            #pragma unroll
            for (int k = 0; k < H; ++k) s += Wfc[(size_t)tid * H + k] * h1s[r][k];
            out[(size_t)(b0 + r) * ODIM + tid] = s;
        }
    }
}

extern "C" void kernel_launch(void* const* d_in, const int* in_sizes, int n_in,
                              void* d_out, int out_size, void* d_ws, size_t ws_size,
                              hipStream_t stream) {
    const float* x    = (const float*)d_in[0];
    const float* wih0 = (const float*)d_in[1];
    const float* whh0 = (const float*)d_in[2];
    const float* bih0 = (const float*)d_in[3];
    const float* bhh0 = (const float*)d_in[4];
    const float* wih1 = (const float*)d_in[5];
    const float* whh1 = (const float*)d_in[6];
    const float* bih1 = (const float*)d_in[7];
    const float* bhh1 = (const float*)d_in[8];
    const float* wfc  = (const float*)d_in[9];
    const float* bfc  = (const float*)d_in[10];
    float* outp = (float*)d_out;
    float* XP = (float*)d_ws;   // 131072 x 200 fp32 = 104.86 MB scratch

    dim3 g1(BATCH * TT / BM, (G4 + BN - 1) / BN);   // (1024, 4)
    xproj_gemm<<<g1, 256, 0, stream>>>(x, wih0, XP);
    lstm_persist<<<BATCH / 2, 256, 0, stream>>>(XP, whh0, wih1, whh1,
                                                bih0, bhh0, bih1, bhh1,
                                                wfc, bfc, outp);
}